// Round 15
// baseline (542.620 us; speedup 1.0000x reference)
//
#include <hip/hip_runtime.h>
#include <hip/hip_bf16.h>

typedef unsigned char u8;
typedef unsigned short u16;
typedef unsigned int u32;
typedef float f32x2 __attribute__((ext_vector_type(2)));
typedef float f32x4 __attribute__((ext_vector_type(4)));
typedef short bf16x8 __attribute__((ext_vector_type(8)));
typedef short bf16x4 __attribute__((ext_vector_type(4)));
typedef unsigned int u32x4 __attribute__((ext_vector_type(4)));

#define NTOK 392      // tokens per window (8*7*7)
#define CDIM 256
#define TOKS 50176    // total tokens (= 128 windows * 392)
#define BKP  400      // padded key stride (elements) in masked-bias table (global)
#define MSP  404      // LDS stride for Ms rows: 101 dwords (odd) -> conflict-free reads
#define VTP  408      // padded Vt LDS row (k dim)
#define LOG2E 1.4426950408889634f

__device__ __forceinline__ u16 f2b(float x) {
  union { __hip_bfloat16 b; u16 u; } cv; cv.b = __float2bfloat16(x); return cv.u;
}
__device__ __forceinline__ float b2f(u16 u) {
  union { unsigned int i; float f; } c; c.i = ((unsigned int)u) << 16; return c.f;
}
__device__ __forceinline__ float exp2_fast(float x) {
#if __has_builtin(__builtin_amdgcn_exp2f)
  return __builtin_amdgcn_exp2f(x);
#else
  float r; asm("v_exp_f32 %0, %1" : "=v"(r) : "v"(x)); return r;
#endif
}

// ---- fp8 e4m3fn encode (cold) / decode (hot) ----
__device__ __forceinline__ u8 f2e4m3(float x) {
  float ax = fabsf(x);
  u32 s = (x < 0.f) ? 0x80u : 0u;
  if (ax >= 448.f) return (u8)(s | 0x7E);        // clamp to +-448 (max finite)
  int e; float m = frexpf(ax, &e);               // ax = m * 2^e, m in [0.5,1)
  int E = e - 1;
  if (E < -6) {                                  // subnormal: val = q * 2^-9
    int q = (int)rintf(ax * 512.f);
    return (u8)(s | q);
  }
  int q = (int)rintf(m * 16.f) - 8;              // 0..8
  if (q == 8) { q = 0; E += 1; if (E > 8) return (u8)(s | 0x7E); }
  return (u8)(s | ((E + 7) << 3) | q);
}
__device__ __forceinline__ float e4m3f(u32 b) {
  u32 s = (b & 0x80u) << 24;
  u32 e = (b >> 3) & 15u, m = b & 7u;
  if (e) { union { u32 u; float f; } c; c.u = s | ((e + 120u) << 23) | (m << 20); return c.f; }
  float v = (float)m * 0x1p-9f;
  return s ? -v : v;
}
__device__ __forceinline__ void fp8x4_to_f32x4(u32 w, f32x4* out) {
#if __has_builtin(__builtin_amdgcn_cvt_pk_f32_fp8)
  f32x2 lo = __builtin_amdgcn_cvt_pk_f32_fp8(w, false);
  f32x2 hi = __builtin_amdgcn_cvt_pk_f32_fp8(w, true);
  (*out)[0] = lo[0]; (*out)[1] = lo[1]; (*out)[2] = hi[0]; (*out)[3] = hi[1];
#else
  (*out)[0] = e4m3f(w & 255); (*out)[1] = e4m3f((w >> 8) & 255);
  (*out)[2] = e4m3f((w >> 16) & 255); (*out)[3] = e4m3f(w >> 24);
#endif
}

__device__ __forceinline__ f32x4 mfma16(bf16x4 a, bf16x4 b, f32x4 c) {
#if __has_builtin(__builtin_amdgcn_mfma_f32_16x16x16bf16_1k)
  return __builtin_amdgcn_mfma_f32_16x16x16bf16_1k(a, b, c, 0, 0, 0);
#else
  asm volatile("v_mfma_f32_16x16x16_bf16 %0, %1, %2, %0"
               : "+v"(c) : "v"(a), "v"(b));
  return c;
#endif
}

// ---------------- fused fp32 -> bf16 weight convert (all 4 weights) ----------------
__global__ void wconv_kernel(const float* __restrict__ a, const float* __restrict__ b,
                             const float* __restrict__ c, const float* __restrict__ d,
                             u16* __restrict__ out) {
  int i = blockIdx.x * 256 + threadIdx.x;          // 786432 total
  const float* src; int off;
  if (i < 196608)      { src = a; off = i; }
  else if (i < 262144) { src = b; off = i - 196608; }
  else if (i < 524288) { src = c; off = i - 262144; }
  else                 { src = d; off = i - 524288; }
  out[i] = f2b(src[off]);
}

// ---------------- LN1: fp32 in, fused roll+window-partition, 4 tokens/block ----------------
__global__ __launch_bounds__(256) void ln1_kernel(const float* __restrict__ x,
    const float* __restrict__ g, const float* __restrict__ b,
    u16* __restrict__ out) {
  const int t = blockIdx.x * 4 + (threadIdx.x >> 6), lane = threadIdx.x & 63;
  int w = t / NTOK, n = t % NTOK;
  int wd = w >> 6, wh = (w >> 3) & 7, ww = w & 7;
  int td = n / 49, rr = n % 49, th = rr / 7, tw = rr % 7;
  int d  = (wd * 8 + td + 4) & 15;
  int hh = (wh * 7 + th + 3) % 56;
  int wc = (ww * 7 + tw + 3) % 56;
  size_t src = ((size_t)((d * 56 + hh) * 56 + wc)) * CDIM;
  f32x4 v = *(const f32x4*)(x + src + lane * 4);
  float s  = v[0] + v[1] + v[2] + v[3];
  float s2 = v[0]*v[0] + v[1]*v[1] + v[2]*v[2] + v[3]*v[3];
  #pragma unroll
  for (int o = 1; o < 64; o <<= 1) { s += __shfl_xor(s, o); s2 += __shfl_xor(s2, o); }
  float mean = s * (1.f / CDIM);
  float var  = s2 * (1.f / CDIM) - mean * mean;
  float rs   = rsqrtf(var + 1e-5f);
  f32x4 gg = *(const f32x4*)(g + lane * 4);
  f32x4 bb = *(const f32x4*)(b + lane * 4);
  bf16x4 o4;
  #pragma unroll
  for (int j = 0; j < 4; ++j) o4[j] = (short)f2b((v[j] - mean) * rs * gg[j] + bb[j]);
  *(bf16x4*)(out + (size_t)t * CDIM + lane * 4) = o4;
}

// ---------------- LN2: bf16 in, linear, 4 tokens/block ----------------
__global__ __launch_bounds__(256) void ln2_kernel(const u16* __restrict__ x,
    const float* __restrict__ g, const float* __restrict__ b,
    u16* __restrict__ out) {
  const int t = blockIdx.x * 4 + (threadIdx.x >> 6), lane = threadIdx.x & 63;
  bf16x4 v4 = *(const bf16x4*)(x + (size_t)t * CDIM + lane * 4);
  f32x4 v;
  #pragma unroll
  for (int j = 0; j < 4; ++j) v[j] = b2f((u16)v4[j]);
  float s  = v[0] + v[1] + v[2] + v[3];
  float s2 = v[0]*v[0] + v[1]*v[1] + v[2]*v[2] + v[3]*v[3];
  #pragma unroll
  for (int o = 1; o < 64; o <<= 1) { s += __shfl_xor(s, o); s2 += __shfl_xor(s2, o); }
  float mean = s * (1.f / CDIM);
  float var  = s2 * (1.f / CDIM) - mean * mean;
  float rs   = rsqrtf(var + 1e-5f);
  f32x4 gg = *(const f32x4*)(g + lane * 4);
  f32x4 bb = *(const f32x4*)(b + lane * 4);
  bf16x4 o4;
  #pragma unroll
  for (int j = 0; j < 4; ++j) o4[j] = (short)f2b((v[j] - mean) * rs * gg[j] + bb[j]);
  *(bf16x4*)(out + (size_t)t * CDIM + lane * 4) = o4;
}

// ---- masked-bias table: mb[pat][h][q=392][k=BKP] fp8-e4m3, value=(bias+mask)*log2e ----
__global__ void mb_kernel(const float* __restrict__ rel, u8* __restrict__ mb) {
  int idx = blockIdx.x * 256 + threadIdx.x;          // over 8 * 392 * 400
  if (idx >= 8 * NTOK * BKP) return;
  int pat = idx / (NTOK * BKP);
  int r   = idx % (NTOK * BKP);
  int q = r / BKP, k = r % BKP;
  int pd = (pat >> 2) & 1, ph = (pat >> 1) & 1, pw = pat & 1;
  if (k >= NTOK) {
    #pragma unroll
    for (int h = 0; h < 8; ++h)
      mb[((size_t)(pat * 8 + h) * NTOK + q) * BKP + k] = 0xFE;   // -448 -> exp2 ~ 0
    return;
  }
  int td = q / 49, th = (q % 49) / 7, tw = q % 7;
  int md = k / 49, mh = (k % 49) / 7, mw = k % 7;
  int cq = (pd ? (td < 4 ? 1 : 2) : 0) * 9 + (ph ? (th < 4 ? 1 : 2) : 0) * 3 + (pw ? (tw < 4 ? 1 : 2) : 0);
  int ck = (pd ? (md < 4 ? 1 : 2) : 0) * 9 + (ph ? (mh < 4 ? 1 : 2) : 0) * 3 + (pw ? (mw < 4 ? 1 : 2) : 0);
  float mask = (cq == ck) ? 0.f : -100.f;
  int ridx = (td - md + 7) * 169 + (th - mh + 6) * 13 + (tw - mw + 6);
  const float* rp = rel + (size_t)ridx * 8;
  #pragma unroll
  for (int h = 0; h < 8; ++h)
    mb[((size_t)(pat * 8 + h) * NTOK + q) * BKP + k] = f2e4m3((rp[h] + mask) * LOG2E);
}

// ---------------- generic bf16 GEMM: C[M][N] = A[M][K] * B[N][K]^T ----------------
// m97 structure + XCD remap + 5 blocks/CU (32KB LDS x5 = 160KB; VGPR<=102).
// MFMA operands SWAPPED (computes C^T): per lane acc[mi][ni] holds row
// bm+wm+mi*16+l16 x 4 contiguous cols -> wide vector store epilogues.
template<int K, class Epi>
__global__ __launch_bounds__(256, 5) void gemm_bt(const u16* __restrict__ A,
    const u16* __restrict__ B, int nx, Epi epi) {
  __shared__ __align__(16) u16 As[128 * 64];
  __shared__ __align__(16) u16 Bs[128 * 64];
  const int nwg = gridDim.x;
  const int q8 = nwg >> 3, r8 = nwg & 7;
  const int xcd = blockIdx.x & 7, bix = blockIdx.x >> 3;
  const int logical = (xcd < r8) ? (xcd * (q8 + 1) + bix)
                                 : (r8 * (q8 + 1) + (xcd - r8) * q8 + bix);
  const int bm = (logical / nx) * 128, bn = (logical % nx) * 128;
  const int tid = threadIdx.x, lane = tid & 63, wv = tid >> 6;
  const int wm = (wv >> 1) * 64, wn = (wv & 1) * 64;
  const int l16 = lane & 15, g = lane >> 4;
  const int sw = l16 & 7;
  const int srow = (lane >> 3);             // row within 8-row group
  const int scc  = (lane & 7) ^ srow;       // swizzled source chunk
  f32x4 acc[4][4];
  #pragma unroll
  for (int i = 0; i < 4; ++i)
    #pragma unroll
    for (int j = 0; j < 4; ++j) acc[i][j] = (f32x4){0.f, 0.f, 0.f, 0.f};
  #pragma unroll
  for (int k0 = 0; k0 < K; k0 += 64) {
    #pragma unroll
    for (int c = 0; c < 4; ++c) {
      int row = wv * 32 + c * 8 + srow;
      const u16* ga = A + (size_t)(bm + row) * K + k0 + scc * 8;
      const u16* gb = B + (size_t)(bn + row) * K + k0 + scc * 8;
      __builtin_amdgcn_global_load_lds(
          (const __attribute__((address_space(1))) void*)ga,
          (__attribute__((address_space(3))) void*)(As + (wv * 32 + c * 8) * 64), 16, 0, 0);
      __builtin_amdgcn_global_load_lds(
          (const __attribute__((address_space(1))) void*)gb,
          (__attribute__((address_space(3))) void*)(Bs + (wv * 32 + c * 8) * 64), 16, 0, 0);
    }
    __syncthreads();
    #pragma unroll
    for (int kk = 0; kk < 2; ++kk) {
      bf16x8 fa[4], fb[4];
      #pragma unroll
      for (int i = 0; i < 4; ++i)
        fa[i] = *(const bf16x8*)(As + (wm + i * 16 + l16) * 64 + (((kk * 4 + g) ^ sw) * 8));
      #pragma unroll
      for (int i = 0; i < 4; ++i)
        fb[i] = *(const bf16x8*)(Bs + (wn + i * 16 + l16) * 64 + (((kk * 4 + g) ^ sw) * 8));
      #pragma unroll
      for (int mi = 0; mi < 4; ++mi)
        #pragma unroll
        for (int ni = 0; ni < 4; ++ni)
          acc[mi][ni] = __builtin_amdgcn_mfma_f32_16x16x32_bf16(fb[ni], fa[mi], acc[mi][ni], 0, 0, 0);
    }
    __syncthreads();
  }
  #pragma unroll
  for (int mi = 0; mi < 4; ++mi) {
    const int row = bm + wm + mi * 16 + l16;
    #pragma unroll
    for (int ni = 0; ni < 4; ++ni)
      epi(row, bn + wn + ni * 16 + g * 4, acc[mi][ni]);
  }
}

// ---------------- epilogues (receive 4 contiguous cols per call) ----------------
struct EpiQKV {  // q/k: [w][h][n][32] (bf16x4 store); v: [w][h][32][n] (4 strided)
  const float* __restrict__ qb;
  u16 *q, *k, *v;
  __device__ void operator()(int row, int col, f32x4 val) const {
    f32x4 b4 = *(const f32x4*)(qb + col);
    int which = col >> 8, hd = col & 255;
    int head = hd >> 5, d = hd & 31;
    int w = row / NTOK, n = row - w * NTOK;
    if (which == 2) {
      u16* p = v + (((size_t)w * 8 + head) * 32 + d) * NTOK + n;
      #pragma unroll
      for (int j = 0; j < 4; ++j) p[(size_t)j * NTOK] = f2b(val[j] + b4[j]);
    } else {
      const float sc = (which == 0) ? 0.17677669529663687f * LOG2E : 1.f;
      bf16x4 o;
      #pragma unroll
      for (int j = 0; j < 4; ++j) o[j] = (short)f2b((val[j] + b4[j]) * sc);
      u16* p = (which == 0 ? q : k) + (((size_t)w * 8 + head) * NTOK + n) * 32 + d;
      *(bf16x4*)p = o;
    }
  }
};

struct EpiProj {  // +bias, reverse-partition + unroll, + residual x -> xres (bf16)
  const float* __restrict__ pb;
  const float* __restrict__ x;
  u16* xr;
  __device__ void operator()(int row, int col, f32x4 val) const {
    f32x4 b4 = *(const f32x4*)(pb + col);
    int w = row / NTOK, n = row - w * NTOK;
    int wd = w >> 6, wh = (w >> 3) & 7, ww = w & 7;
    int td = n / 49, rr = n % 49, th = rr / 7, tw = rr % 7;
    int d  = (wd * 8 + td + 4) & 15;
    int hh = (wh * 7 + th + 3) % 56;
    int wc = (ww * 7 + tw + 3) % 56;
    size_t t = ((size_t)((d * 56 + hh) * 56 + wc)) * CDIM + col;
    f32x4 xv = *(const f32x4*)(x + t);
    bf16x4 o;
    #pragma unroll
    for (int j = 0; j < 4; ++j) o[j] = (short)f2b(xv[j] + val[j] + b4[j]);
    *(bf16x4*)(xr + t) = o;
  }
};

struct EpiFC1 {  // +bias, exact GELU, bf16x4 store (row stride 1024)
  const float* __restrict__ fb;
  u16* y;
  __device__ void operator()(int row, int col, f32x4 val) const {
    f32x4 b4 = *(const f32x4*)(fb + col);
    bf16x4 o;
    #pragma unroll
    for (int j = 0; j < 4; ++j) {
      float u = val[j] + b4[j];
      u = 0.5f * u * (1.0f + erff(u * 0.70710678118654752f));
      o[j] = (short)f2b(u);
    }
    *(bf16x4*)(y + (size_t)row * 1024 + col) = o;
  }
};

struct EpiFC2 {  // +bias, + residual xres (bf16), fp32x4 final out
  const float* __restrict__ fb;
  const u16* __restrict__ xr;
  float* out;
  __device__ void operator()(int row, int col, f32x4 val) const {
    f32x4 b4 = *(const f32x4*)(fb + col);
    size_t t = (size_t)row * CDIM + col;
    bf16x4 xv = *(const bf16x4*)(xr + t);
    f32x4 o;
    #pragma unroll
    for (int j = 0; j < 4; ++j) o[j] = b2f((u16)xv[j]) + val[j] + b4[j];
    *(f32x4*)(out + t) = o;
  }
};

// ---------------- window attention (round-13 structure, Ms stride 404) ----------------
// Block-synchronous q-tile rounds with T14 async-STAGE split for the mb slice.
// Ms LDS stride = 404 B = 101 dwords (odd) -> per-step u32 reads hit all 32
// banks (worst 2-way = free); staging writes ~3-way instead of 8-way.
__global__ __launch_bounds__(256, 2) void attn_kernel(
    const u16* __restrict__ qb, const u16* __restrict__ kb,
    const u16* __restrict__ vb, const u8* __restrict__ mb,
    u16* __restrict__ out) {
  __shared__ __align__(16) u16 Ks[25 * 512];     // 25600 B
  __shared__ __align__(16) u16 Vt[32 * VTP];     // 26112 B
  __shared__ __align__(16) u8  Ms[64 * MSP];     // 25856 B fp8 slice (stride 404)
  const int h = blockIdx.x & 7;
  const int r = blockIdx.x >> 3;
  const int cum[9] = {0, 49, 56, 63, 64, 113, 120, 127, 128};
  int pat = 0;
  #pragma unroll
  for (int p = 0; p < 8; ++p) pat += (r >= cum[p + 1]) ? 1 : 0;
  const int i = r - cum[pat];
  const int pd = (pat >> 2) & 1, ph = (pat >> 1) & 1, pw = pat & 1;
  const int nw = pw ? 1 : 7;
  const int wh = ph ? 7 : i / nw;
  const int ww = pw ? 7 : i % nw;
  const int w = pd * 64 + wh * 8 + ww;

  const int tid = threadIdx.x, lane = tid & 63, wv = tid >> 6;
  const size_t base = (size_t)(w * 8 + h) * (NTOK * 32);
  const u8* mplane = mb + (size_t)(pat * 8 + h) * NTOK * BKP;

  // zero Vt pad cols (keys 392..407)
  for (int idx = tid; idx < 32 * 16; idx += 256)
    Vt[(idx >> 4) * VTP + NTOK + (idx & 15)] = 0;
  // stage K tiled+swizzled (400 rows; rows>=392 clamp -> finite; bias kills them)
  for (int c = tid; c < 400 * 4; c += 256) {
    int rr = c >> 2, cb = c & 3;
    int rs = rr < NTOK ? rr : NTOK - 1;
    *(bf16x8*)(Ks + (rr >> 4) * 512 + cb * 128 + (((rr & 15) ^ (cb << 1)) * 8)) =
        *(const bf16x8*)(kb + base + (size_t)rs * 32 + cb * 8);
  }
  // stage V rows (vbuf pre-transposed [w][h][32][392]): coalesced copies
  for (int c = tid; c < 32 * 49; c += 256) {
    int d = c / 49, ch = c % 49;
    *(bf16x8*)(Vt + d * VTP + ch * 8) =
        *(const bf16x8*)(vb + base + (size_t)d * NTOK + ch * 8);
  }

  // prefetch round-0 mb slice into registers (1600 x 16B chunks)
  u32x4 pf[7];
  #pragma unroll
  for (int j = 0; j < 7; ++j) {
    int idx = tid + j * 256;
    if (idx < 1600) {
      int row = idx / 25, cb = idx % 25;
      pf[j] = *(const u32x4*)(mplane + (size_t)row * BKP + cb * 16);
    }
  }

  const int l16 = lane & 15, g = lane >> 4;
  for (int round = 0; round < 7; ++round) {
    // write this round's slice to LDS (prior round's reads fenced by loop-end barrier)
    #pragma unroll
    for (int j = 0; j < 7; ++j) {
      int idx = tid + j * 256;
      if (idx < 1600) {
        int row = idx / 25, cb = idx % 25;
        u32* dst = (u32*)(Ms + row * MSP + cb * 16);
        dst[0] = pf[j][0]; dst[1] = pf[j][1]; dst[2] = pf[j][2]; dst[3] = pf[j][3];
      }
    }
    // issue next round's loads (overlap with compute below)
    if (round < 6) {
      #pragma unroll
      for (int j = 0; j < 7; ++j) {
        int idx = tid + j * 256;
        if (idx < 1600) {
          int row = idx / 25, cb = idx % 25;
          int qrow = (round + 1) * 64 + row; qrow = qrow < NTOK ? qrow : NTOK - 1;
          pf[j] = *(const u32x4*)(mplane + (size_t)qrow * BKP + cb * 16);
        }
      }
    }
    __syncthreads();
    const int qt = round * 4 + wv;
    if (qt < 25) {
      const int qq = qt * 16 + l16;
      const int qc = qq < NTOK ? qq : NTOK - 1;
      const bf16x8 qf = *(const bf16x8*)(qb + base + (size_t)qc * 32 + g * 8);
      const u8* mrow = Ms + (wv * 16 + l16) * MSP + 4 * g;
      f32x4 o00 = {0.f,0.f,0.f,0.f}, o01 = {0.f,0.f,0.f,0.f};
      f32x4 o10 = {0.f,0.f,0.f,0.f}, o11 = {0.f,0.f,0.f,0.f};
      float psum = 0.f;
      #pragma unroll
      for (int t = 0; t < 25; ++t) {
        bf16x8 kf = *(const bf16x8*)(Ks + t * 512 + g * 128 + ((l16 ^ (g << 1)) * 8));
        u32 mw = *(const u32*)(mrow + t * 16);
        f32x4 c;
        fp8x4_to_f32x4(mw, &c);
        f32x4 st = __builtin_amdgcn_mfma_f32_16x16x32_bf16(kf, qf, c, 0, 0, 0);
        float p0 = exp2_fast(st[0]), p1 = exp2_fast(st[1]);
        float p2 = exp2_fast(st[2]), p3 = exp2_fast(st[3]);
        psum += (p0 + p1) + (p2 + p3);
        bf16x4 pfv;
        pfv[0] = (short)f2b(p0); pfv[1] = (short)f2b(p1);
        pfv[2] = (short)f2b(p2); pfv[3] = (short)f2b(p3);
        bf16x4 v0 = *(const bf16x4*)(Vt + l16 * VTP + t * 16 + 4 * g);
        bf16x4 v1 = *(const bf16x4*)(Vt + (16 + l16) * VTP + t * 16 + 4 * g);
        if (t & 1) { o01 = mfma16(v0, pfv, o01); o11 = mfma16(v1, pfv, o11); }
        else       { o00 = mfma16(v0, pfv, o00); o10 = mfma16(v1, pfv, o10); }
      }
      psum += __shfl_xor(psum, 16);
      psum += __shfl_xor(psum, 32);
      if (qq < NTOK) {
        float inv = 1.f / psum;
        bf16x4 w0, w1;
        #pragma unroll
        for (int j = 0; j < 4; ++j) {
          w0[j] = (short)f2b((o00[j] + o01[j]) * inv);
          w1[j] = (short)f2b((o10[j] + o11[j]) * inv);
        }
        u16* op = out + ((size_t)(w * NTOK + qq)) * CDIM + h * 32;
        *(bf16x4*)(op + 4 * g) = w0;
        *(bf16x4*)(op + 16 + 4 * g) = w1;
      }
    }
    __syncthreads();
  }
}

// ---------------- launcher ----------------
extern "C" void kernel_launch(void* const* d_in, const int* in_sizes, int n_in,
                              void* d_out, int out_size, void* d_ws, size_t ws_size,
                              hipStream_t stream) {
  const float* x      = (const float*)d_in[0];
  const float* n1g    = (const float*)d_in[1];
  const float* n1b    = (const float*)d_in[2];
  const float* qkv_w  = (const float*)d_in[3];
  const float* qkv_b  = (const float*)d_in[4];
  const float* rel    = (const float*)d_in[5];
  const float* proj_w = (const float*)d_in[6];
  const float* proj_b = (const float*)d_in[7];
  const float* n2g    = (const float*)d_in[8];
  const float* n2b    = (const float*)d_in[9];
  const float* fc1_w  = (const float*)d_in[10];
  const float* fc1_b  = (const float*)d_in[11];
  const float* fc2_w  = (const float*)d_in[12];
  const float* fc2_b  = (const float*)d_in[13];
  float* out = (float*)d_out;
  char* ws = (char*)d_ws;

  const size_t PL = (size_t)TOKS * CDIM * 2;            // 25,690,112 B
  const size_t MBSZ = (size_t)8 * 8 * NTOK * BKP;       // 10,035,200 B (fp8)
  u16*   wins = (u16*)(ws);
  u16*   aout = (u16*)(ws + PL);
  u8*    mbuf = (u8*)(ws + 2 * PL);
  u16*   qbuf = (u16*)(ws + 2 * PL + MBSZ);
  u16*   kbuf = (u16*)(ws + 4 * PL);
  u16*   vbuf = (u16*)(ws + 5 * PL);
  u16*   xres = (u16*)(ws + 4 * PL);                    // bf16; kbuf dead by proj
  u16*   h2   = (u16*)(ws + 6 * PL);
  u16*   wq   = (u16*)(ws + 7 * PL);
  u16*   y1   = (u16*)(ws);

  wconv_kernel<<<3072, 256, 0, stream>>>(qkv_w, proj_w, fc1_w, fc2_w, wq);
  mb_kernel<<<(8 * NTOK * BKP + 255) / 256, 256, 0, stream>>>(rel, mbuf);
  ln1_kernel<<<TOKS / 4, 256, 0, stream>>>(x, n1g, n1b, wins);
  gemm_bt<256><<<2352, 256, 0, stream>>>(wins, wq, 6, EpiQKV{qkv_b, qbuf, kbuf, vbuf});
  attn_kernel<<<1024, 256, 0, stream>>>(qbuf, kbuf, vbuf, mbuf, aout);
  gemm_bt<256><<<784, 256, 0, stream>>>(aout, wq + 196608, 2, EpiProj{proj_b, x, xres});
  ln2_kernel<<<TOKS / 4, 256, 0, stream>>>(xres, n2g, n2b, h2);
  gemm_bt<256><<<3136, 256, 0, stream>>>(h2, wq + 262144, 8, EpiFC1{fc1_b, y1});
  gemm_bt<1024><<<784, 256, 0, stream>>>(y1, wq + 524288, 2, EpiFC2{fc2_b, xres, out});
}

// Round 16
// 272.356 us; speedup vs baseline: 1.9923x; 1.9923x over previous
//
#include <hip/hip_runtime.h>
#include <hip/hip_bf16.h>

typedef unsigned char u8;
typedef unsigned short u16;
typedef unsigned int u32;
typedef float f32x2 __attribute__((ext_vector_type(2)));
typedef float f32x4 __attribute__((ext_vector_type(4)));
typedef short bf16x8 __attribute__((ext_vector_type(8)));
typedef short bf16x4 __attribute__((ext_vector_type(4)));
typedef unsigned int u32x4 __attribute__((ext_vector_type(4)));

#define NTOK 392      // tokens per window (8*7*7)
#define CDIM 256
#define TOKS 50176    // total tokens (= 128 windows * 392)
#define BKP  400      // padded key stride (elements) in masked-bias table (global)
#define MSP  404      // LDS stride for Ms rows: 101 dwords (odd) -> conflict-free reads
#define VTP  408      // padded Vt LDS row (k dim)
#define LOG2E 1.4426950408889634f

__device__ __forceinline__ u16 f2b(float x) {
  union { __hip_bfloat16 b; u16 u; } cv; cv.b = __float2bfloat16(x); return cv.u;
}
__device__ __forceinline__ float b2f(u16 u) {
  union { unsigned int i; float f; } c; c.i = ((unsigned int)u) << 16; return c.f;
}
__device__ __forceinline__ float exp2_fast(float x) {
#if __has_builtin(__builtin_amdgcn_exp2f)
  return __builtin_amdgcn_exp2f(x);
#else
  float r; asm("v_exp_f32 %0, %1" : "=v"(r) : "v"(x)); return r;
#endif
}

// ---- fp8 e4m3fn encode (cold) / decode (hot) ----
__device__ __forceinline__ u8 f2e4m3(float x) {
  float ax = fabsf(x);
  u32 s = (x < 0.f) ? 0x80u : 0u;
  if (ax >= 448.f) return (u8)(s | 0x7E);        // clamp to +-448 (max finite)
  int e; float m = frexpf(ax, &e);               // ax = m * 2^e, m in [0.5,1)
  int E = e - 1;
  if (E < -6) {                                  // subnormal: val = q * 2^-9
    int q = (int)rintf(ax * 512.f);
    return (u8)(s | q);
  }
  int q = (int)rintf(m * 16.f) - 8;              // 0..8
  if (q == 8) { q = 0; E += 1; if (E > 8) return (u8)(s | 0x7E); }
  return (u8)(s | ((E + 7) << 3) | q);
}
__device__ __forceinline__ float e4m3f(u32 b) {
  u32 s = (b & 0x80u) << 24;
  u32 e = (b >> 3) & 15u, m = b & 7u;
  if (e) { union { u32 u; float f; } c; c.u = s | ((e + 120u) << 23) | (m << 20); return c.f; }
  float v = (float)m * 0x1p-9f;
  return s ? -v : v;
}
__device__ __forceinline__ void fp8x4_to_f32x4(u32 w, f32x4* out) {
#if __has_builtin(__builtin_amdgcn_cvt_pk_f32_fp8)
  f32x2 lo = __builtin_amdgcn_cvt_pk_f32_fp8(w, false);
  f32x2 hi = __builtin_amdgcn_cvt_pk_f32_fp8(w, true);
  (*out)[0] = lo[0]; (*out)[1] = lo[1]; (*out)[2] = hi[0]; (*out)[3] = hi[1];
#else
  (*out)[0] = e4m3f(w & 255); (*out)[1] = e4m3f((w >> 8) & 255);
  (*out)[2] = e4m3f((w >> 16) & 255); (*out)[3] = e4m3f(w >> 24);
#endif
}

__device__ __forceinline__ f32x4 mfma16(bf16x4 a, bf16x4 b, f32x4 c) {
#if __has_builtin(__builtin_amdgcn_mfma_f32_16x16x16bf16_1k)
  return __builtin_amdgcn_mfma_f32_16x16x16bf16_1k(a, b, c, 0, 0, 0);
#else
  asm volatile("v_mfma_f32_16x16x16_bf16 %0, %1, %2, %0"
               : "+v"(c) : "v"(a), "v"(b));
  return c;
#endif
}

// ---------------- fused fp32 -> bf16 weight convert (all 4 weights) ----------------
__global__ void wconv_kernel(const float* __restrict__ a, const float* __restrict__ b,
                             const float* __restrict__ c, const float* __restrict__ d,
                             u16* __restrict__ out) {
  int i = blockIdx.x * 256 + threadIdx.x;          // 786432 total
  const float* src; int off;
  if (i < 196608)      { src = a; off = i; }
  else if (i < 262144) { src = b; off = i - 196608; }
  else if (i < 524288) { src = c; off = i - 262144; }
  else                 { src = d; off = i - 524288; }
  out[i] = f2b(src[off]);
}

// ---------------- LN1: fp32 in, fused roll+window-partition, 4 tokens/block ----------------
__global__ __launch_bounds__(256) void ln1_kernel(const float* __restrict__ x,
    const float* __restrict__ g, const float* __restrict__ b,
    u16* __restrict__ out) {
  const int t = blockIdx.x * 4 + (threadIdx.x >> 6), lane = threadIdx.x & 63;
  int w = t / NTOK, n = t % NTOK;
  int wd = w >> 6, wh = (w >> 3) & 7, ww = w & 7;
  int td = n / 49, rr = n % 49, th = rr / 7, tw = rr % 7;
  int d  = (wd * 8 + td + 4) & 15;
  int hh = (wh * 7 + th + 3) % 56;
  int wc = (ww * 7 + tw + 3) % 56;
  size_t src = ((size_t)((d * 56 + hh) * 56 + wc)) * CDIM;
  f32x4 v = *(const f32x4*)(x + src + lane * 4);
  float s  = v[0] + v[1] + v[2] + v[3];
  float s2 = v[0]*v[0] + v[1]*v[1] + v[2]*v[2] + v[3]*v[3];
  #pragma unroll
  for (int o = 1; o < 64; o <<= 1) { s += __shfl_xor(s, o); s2 += __shfl_xor(s2, o); }
  float mean = s * (1.f / CDIM);
  float var  = s2 * (1.f / CDIM) - mean * mean;
  float rs   = rsqrtf(var + 1e-5f);
  f32x4 gg = *(const f32x4*)(g + lane * 4);
  f32x4 bb = *(const f32x4*)(b + lane * 4);
  bf16x4 o4;
  #pragma unroll
  for (int j = 0; j < 4; ++j) o4[j] = (short)f2b((v[j] - mean) * rs * gg[j] + bb[j]);
  *(bf16x4*)(out + (size_t)t * CDIM + lane * 4) = o4;
}

// ---------------- LN2: bf16 in, linear, 4 tokens/block ----------------
__global__ __launch_bounds__(256) void ln2_kernel(const u16* __restrict__ x,
    const float* __restrict__ g, const float* __restrict__ b,
    u16* __restrict__ out) {
  const int t = blockIdx.x * 4 + (threadIdx.x >> 6), lane = threadIdx.x & 63;
  bf16x4 v4 = *(const bf16x4*)(x + (size_t)t * CDIM + lane * 4);
  f32x4 v;
  #pragma unroll
  for (int j = 0; j < 4; ++j) v[j] = b2f((u16)v4[j]);
  float s  = v[0] + v[1] + v[2] + v[3];
  float s2 = v[0]*v[0] + v[1]*v[1] + v[2]*v[2] + v[3]*v[3];
  #pragma unroll
  for (int o = 1; o < 64; o <<= 1) { s += __shfl_xor(s, o); s2 += __shfl_xor(s2, o); }
  float mean = s * (1.f / CDIM);
  float var  = s2 * (1.f / CDIM) - mean * mean;
  float rs   = rsqrtf(var + 1e-5f);
  f32x4 gg = *(const f32x4*)(g + lane * 4);
  f32x4 bb = *(const f32x4*)(b + lane * 4);
  bf16x4 o4;
  #pragma unroll
  for (int j = 0; j < 4; ++j) o4[j] = (short)f2b((v[j] - mean) * rs * gg[j] + bb[j]);
  *(bf16x4*)(out + (size_t)t * CDIM + lane * 4) = o4;
}

// ---- masked-bias table: mb[pat][h][q=392][k=BKP] fp8-e4m3, value=(bias+mask)*log2e ----
__global__ void mb_kernel(const float* __restrict__ rel, u8* __restrict__ mb) {
  int idx = blockIdx.x * 256 + threadIdx.x;          // over 8 * 392 * 400
  if (idx >= 8 * NTOK * BKP) return;
  int pat = idx / (NTOK * BKP);
  int r   = idx % (NTOK * BKP);
  int q = r / BKP, k = r % BKP;
  int pd = (pat >> 2) & 1, ph = (pat >> 1) & 1, pw = pat & 1;
  if (k >= NTOK) {
    #pragma unroll
    for (int h = 0; h < 8; ++h)
      mb[((size_t)(pat * 8 + h) * NTOK + q) * BKP + k] = 0xFE;   // -448 -> exp2 ~ 0
    return;
  }
  int td = q / 49, th = (q % 49) / 7, tw = q % 7;
  int md = k / 49, mh = (k % 49) / 7, mw = k % 7;
  int cq = (pd ? (td < 4 ? 1 : 2) : 0) * 9 + (ph ? (th < 4 ? 1 : 2) : 0) * 3 + (pw ? (tw < 4 ? 1 : 2) : 0);
  int ck = (pd ? (md < 4 ? 1 : 2) : 0) * 9 + (ph ? (mh < 4 ? 1 : 2) : 0) * 3 + (pw ? (mw < 4 ? 1 : 2) : 0);
  float mask = (cq == ck) ? 0.f : -100.f;
  int ridx = (td - md + 7) * 169 + (th - mh + 6) * 13 + (tw - mw + 6);
  const float* rp = rel + (size_t)ridx * 8;
  #pragma unroll
  for (int h = 0; h < 8; ++h)
    mb[((size_t)(pat * 8 + h) * NTOK + q) * BKP + k] = f2e4m3((rp[h] + mask) * LOG2E);
}

// ---------------- generic bf16 GEMM: C[M][N] = A[M][K] * B[N][K]^T ----------------
// m97 structure + XCD remap + 4 blocks/CU (VGPR cap 128 >= the 88 needed;
// (256,5) capped VGPR at 48 -> spills, round-15 regression). MFMA operands
// SWAPPED (computes C^T): per lane acc[mi][ni] holds row bm+wm+mi*16+l16 x 4
// contiguous cols -> wide vector store epilogues.
template<int K, class Epi>
__global__ __launch_bounds__(256, 4) void gemm_bt(const u16* __restrict__ A,
    const u16* __restrict__ B, int nx, Epi epi) {
  __shared__ __align__(16) u16 As[128 * 64];
  __shared__ __align__(16) u16 Bs[128 * 64];
  const int nwg = gridDim.x;
  const int q8 = nwg >> 3, r8 = nwg & 7;
  const int xcd = blockIdx.x & 7, bix = blockIdx.x >> 3;
  const int logical = (xcd < r8) ? (xcd * (q8 + 1) + bix)
                                 : (r8 * (q8 + 1) + (xcd - r8) * q8 + bix);
  const int bm = (logical / nx) * 128, bn = (logical % nx) * 128;
  const int tid = threadIdx.x, lane = tid & 63, wv = tid >> 6;
  const int wm = (wv >> 1) * 64, wn = (wv & 1) * 64;
  const int l16 = lane & 15, g = lane >> 4;
  const int sw = l16 & 7;
  const int srow = (lane >> 3);             // row within 8-row group
  const int scc  = (lane & 7) ^ srow;       // swizzled source chunk
  f32x4 acc[4][4];
  #pragma unroll
  for (int i = 0; i < 4; ++i)
    #pragma unroll
    for (int j = 0; j < 4; ++j) acc[i][j] = (f32x4){0.f, 0.f, 0.f, 0.f};
  #pragma unroll
  for (int k0 = 0; k0 < K; k0 += 64) {
    #pragma unroll
    for (int c = 0; c < 4; ++c) {
      int row = wv * 32 + c * 8 + srow;
      const u16* ga = A + (size_t)(bm + row) * K + k0 + scc * 8;
      const u16* gb = B + (size_t)(bn + row) * K + k0 + scc * 8;
      __builtin_amdgcn_global_load_lds(
          (const __attribute__((address_space(1))) void*)ga,
          (__attribute__((address_space(3))) void*)(As + (wv * 32 + c * 8) * 64), 16, 0, 0);
      __builtin_amdgcn_global_load_lds(
          (const __attribute__((address_space(1))) void*)gb,
          (__attribute__((address_space(3))) void*)(Bs + (wv * 32 + c * 8) * 64), 16, 0, 0);
    }
    __syncthreads();
    #pragma unroll
    for (int kk = 0; kk < 2; ++kk) {
      bf16x8 fa[4], fb[4];
      #pragma unroll
      for (int i = 0; i < 4; ++i)
        fa[i] = *(const bf16x8*)(As + (wm + i * 16 + l16) * 64 + (((kk * 4 + g) ^ sw) * 8));
      #pragma unroll
      for (int i = 0; i < 4; ++i)
        fb[i] = *(const bf16x8*)(Bs + (wn + i * 16 + l16) * 64 + (((kk * 4 + g) ^ sw) * 8));
      #pragma unroll
      for (int mi = 0; mi < 4; ++mi)
        #pragma unroll
        for (int ni = 0; ni < 4; ++ni)
          acc[mi][ni] = __builtin_amdgcn_mfma_f32_16x16x32_bf16(fb[ni], fa[mi], acc[mi][ni], 0, 0, 0);
    }
    __syncthreads();
  }
  #pragma unroll
  for (int mi = 0; mi < 4; ++mi) {
    const int row = bm + wm + mi * 16 + l16;
    #pragma unroll
    for (int ni = 0; ni < 4; ++ni)
      epi(row, bn + wn + ni * 16 + g * 4, acc[mi][ni]);
  }
}

// ---------------- epilogues (receive 4 contiguous cols per call) ----------------
struct EpiQKV {  // q/k: [w][h][n][32] (bf16x4 store); v: [w][h][32][n] (4 strided)
  const float* __restrict__ qb;
  u16 *q, *k, *v;
  __device__ void operator()(int row, int col, f32x4 val) const {
    f32x4 b4 = *(const f32x4*)(qb + col);
    int which = col >> 8, hd = col & 255;
    int head = hd >> 5, d = hd & 31;
    int w = row / NTOK, n = row - w * NTOK;
    if (which == 2) {
      u16* p = v + (((size_t)w * 8 + head) * 32 + d) * NTOK + n;
      #pragma unroll
      for (int j = 0; j < 4; ++j) p[(size_t)j * NTOK] = f2b(val[j] + b4[j]);
    } else {
      const float sc = (which == 0) ? 0.17677669529663687f * LOG2E : 1.f;
      bf16x4 o;
      #pragma unroll
      for (int j = 0; j < 4; ++j) o[j] = (short)f2b((val[j] + b4[j]) * sc);
      u16* p = (which == 0 ? q : k) + (((size_t)w * 8 + head) * NTOK + n) * 32 + d;
      *(bf16x4*)p = o;
    }
  }
};

struct EpiProj {  // +bias, reverse-partition + unroll, + residual x -> xres (bf16)
  const float* __restrict__ pb;
  const float* __restrict__ x;
  u16* xr;
  __device__ void operator()(int row, int col, f32x4 val) const {
    f32x4 b4 = *(const f32x4*)(pb + col);
    int w = row / NTOK, n = row - w * NTOK;
    int wd = w >> 6, wh = (w >> 3) & 7, ww = w & 7;
    int td = n / 49, rr = n % 49, th = rr / 7, tw = rr % 7;
    int d  = (wd * 8 + td + 4) & 15;
    int hh = (wh * 7 + th + 3) % 56;
    int wc = (ww * 7 + tw + 3) % 56;
    size_t t = ((size_t)((d * 56 + hh) * 56 + wc)) * CDIM + col;
    f32x4 xv = *(const f32x4*)(x + t);
    bf16x4 o;
    #pragma unroll
    for (int j = 0; j < 4; ++j) o[j] = (short)f2b(xv[j] + val[j] + b4[j]);
    *(bf16x4*)(xr + t) = o;
  }
};

struct EpiFC1 {  // +bias, exact GELU, bf16x4 store (row stride 1024)
  const float* __restrict__ fb;
  u16* y;
  __device__ void operator()(int row, int col, f32x4 val) const {
    f32x4 b4 = *(const f32x4*)(fb + col);
    bf16x4 o;
    #pragma unroll
    for (int j = 0; j < 4; ++j) {
      float u = val[j] + b4[j];
      u = 0.5f * u * (1.0f + erff(u * 0.70710678118654752f));
      o[j] = (short)f2b(u);
    }
    *(bf16x4*)(y + (size_t)row * 1024 + col) = o;
  }
};

struct EpiFC2 {  // +bias, + residual xres (bf16), fp32x4 final out
  const float* __restrict__ fb;
  const u16* __restrict__ xr;
  float* out;
  __device__ void operator()(int row, int col, f32x4 val) const {
    f32x4 b4 = *(const f32x4*)(fb + col);
    size_t t = (size_t)row * CDIM + col;
    bf16x4 xv = *(const bf16x4*)(xr + t);
    f32x4 o;
    #pragma unroll
    for (int j = 0; j < 4; ++j) o[j] = b2f((u16)xv[j]) + val[j] + b4[j];
    *(f32x4*)(out + t) = o;
  }
};

// ---------------- window attention (round-13 structure, Ms stride 404) ----------------
// Block-synchronous q-tile rounds with T14 async-STAGE split for the mb slice.
// Ms LDS stride = 404 B = 101 dwords (odd) -> per-step u32 reads hit all 32
// banks (worst 2-way = free); staging writes ~3-way instead of 8-way.
__global__ __launch_bounds__(256, 2) void attn_kernel(
    const u16* __restrict__ qb, const u16* __restrict__ kb,
    const u16* __restrict__ vb, const u8* __restrict__ mb,
    u16* __restrict__ out) {
  __shared__ __align__(16) u16 Ks[25 * 512];     // 25600 B
  __shared__ __align__(16) u16 Vt[32 * VTP];     // 26112 B
  __shared__ __align__(16) u8  Ms[64 * MSP];     // 25856 B fp8 slice (stride 404)
  const int h = blockIdx.x & 7;
  const int r = blockIdx.x >> 3;
  const int cum[9] = {0, 49, 56, 63, 64, 113, 120, 127, 128};
  int pat = 0;
  #pragma unroll
  for (int p = 0; p < 8; ++p) pat += (r >= cum[p + 1]) ? 1 : 0;
  const int i = r - cum[pat];
  const int pd = (pat >> 2) & 1, ph = (pat >> 1) & 1, pw = pat & 1;
  const int nw = pw ? 1 : 7;
  const int wh = ph ? 7 : i / nw;
  const int ww = pw ? 7 : i % nw;
  const int w = pd * 64 + wh * 8 + ww;

  const int tid = threadIdx.x, lane = tid & 63, wv = tid >> 6;
  const size_t base = (size_t)(w * 8 + h) * (NTOK * 32);
  const u8* mplane = mb + (size_t)(pat * 8 + h) * NTOK * BKP;

  // zero Vt pad cols (keys 392..407)
  for (int idx = tid; idx < 32 * 16; idx += 256)
    Vt[(idx >> 4) * VTP + NTOK + (idx & 15)] = 0;
  // stage K tiled+swizzled (400 rows; rows>=392 clamp -> finite; bias kills them)
  for (int c = tid; c < 400 * 4; c += 256) {
    int rr = c >> 2, cb = c & 3;
    int rs = rr < NTOK ? rr : NTOK - 1;
    *(bf16x8*)(Ks + (rr >> 4) * 512 + cb * 128 + (((rr & 15) ^ (cb << 1)) * 8)) =
        *(const bf16x8*)(kb + base + (size_t)rs * 32 + cb * 8);
  }
  // stage V rows (vbuf pre-transposed [w][h][32][392]): coalesced copies
  for (int c = tid; c < 32 * 49; c += 256) {
    int d = c / 49, ch = c % 49;
    *(bf16x8*)(Vt + d * VTP + ch * 8) =
        *(const bf16x8*)(vb + base + (size_t)d * NTOK + ch * 8);
  }

  // prefetch round-0 mb slice into registers (1600 x 16B chunks)
  u32x4 pf[7];
  #pragma unroll
  for (int j = 0; j < 7; ++j) {
    int idx = tid + j * 256;
    if (idx < 1600) {
      int row = idx / 25, cb = idx % 25;
      pf[j] = *(const u32x4*)(mplane + (size_t)row * BKP + cb * 16);
    }
  }

  const int l16 = lane & 15, g = lane >> 4;
  for (int round = 0; round < 7; ++round) {
    // write this round's slice to LDS (prior round's reads fenced by loop-end barrier)
    #pragma unroll
    for (int j = 0; j < 7; ++j) {
      int idx = tid + j * 256;
      if (idx < 1600) {
        int row = idx / 25, cb = idx % 25;
        u32* dst = (u32*)(Ms + row * MSP + cb * 16);
        dst[0] = pf[j][0]; dst[1] = pf[j][1]; dst[2] = pf[j][2]; dst[3] = pf[j][3];
      }
    }
    // issue next round's loads (overlap with compute below)
    if (round < 6) {
      #pragma unroll
      for (int j = 0; j < 7; ++j) {
        int idx = tid + j * 256;
        if (idx < 1600) {
          int row = idx / 25, cb = idx % 25;
          int qrow = (round + 1) * 64 + row; qrow = qrow < NTOK ? qrow : NTOK - 1;
          pf[j] = *(const u32x4*)(mplane + (size_t)qrow * BKP + cb * 16);
        }
      }
    }
    __syncthreads();
    const int qt = round * 4 + wv;
    if (qt < 25) {
      const int qq = qt * 16 + l16;
      const int qc = qq < NTOK ? qq : NTOK - 1;
      const bf16x8 qf = *(const bf16x8*)(qb + base + (size_t)qc * 32 + g * 8);
      const u8* mrow = Ms + (wv * 16 + l16) * MSP + 4 * g;
      f32x4 o00 = {0.f,0.f,0.f,0.f}, o01 = {0.f,0.f,0.f,0.f};
      f32x4 o10 = {0.f,0.f,0.f,0.f}, o11 = {0.f,0.f,0.f,0.f};
      float psum = 0.f;
      #pragma unroll
      for (int t = 0; t < 25; ++t) {
        bf16x8 kf = *(const bf16x8*)(Ks + t * 512 + g * 128 + ((l16 ^ (g << 1)) * 8));
        u32 mw = *(const u32*)(mrow + t * 16);
        f32x4 c;
        fp8x4_to_f32x4(mw, &c);
        f32x4 st = __builtin_amdgcn_mfma_f32_16x16x32_bf16(kf, qf, c, 0, 0, 0);
        float p0 = exp2_fast(st[0]), p1 = exp2_fast(st[1]);
        float p2 = exp2_fast(st[2]), p3 = exp2_fast(st[3]);
        psum += (p0 + p1) + (p2 + p3);
        bf16x4 pfv;
        pfv[0] = (short)f2b(p0); pfv[1] = (short)f2b(p1);
        pfv[2] = (short)f2b(p2); pfv[3] = (short)f2b(p3);
        bf16x4 v0 = *(const bf16x4*)(Vt + l16 * VTP + t * 16 + 4 * g);
        bf16x4 v1 = *(const bf16x4*)(Vt + (16 + l16) * VTP + t * 16 + 4 * g);
        if (t & 1) { o01 = mfma16(v0, pfv, o01); o11 = mfma16(v1, pfv, o11); }
        else       { o00 = mfma16(v0, pfv, o00); o10 = mfma16(v1, pfv, o10); }
      }
      psum += __shfl_xor(psum, 16);
      psum += __shfl_xor(psum, 32);
      if (qq < NTOK) {
        float inv = 1.f / psum;
        bf16x4 w0, w1;
        #pragma unroll
        for (int j = 0; j < 4; ++j) {
          w0[j] = (short)f2b((o00[j] + o01[j]) * inv);
          w1[j] = (short)f2b((o10[j] + o11[j]) * inv);
        }
        u16* op = out + ((size_t)(w * NTOK + qq)) * CDIM + h * 32;
        *(bf16x4*)(op + 4 * g) = w0;
        *(bf16x4*)(op + 16 + 4 * g) = w1;
      }
    }
    __syncthreads();
  }
}

// ---------------- launcher ----------------
extern "C" void kernel_launch(void* const* d_in, const int* in_sizes, int n_in,
                              void* d_out, int out_size, void* d_ws, size_t ws_size,
                              hipStream_t stream) {
  const float* x      = (const float*)d_in[0];
  const float* n1g    = (const float*)d_in[1];
  const float* n1b    = (const float*)d_in[2];
  const float* qkv_w  = (const float*)d_in[3];
  const float* qkv_b  = (const float*)d_in[4];
  const float* rel    = (const float*)d_in[5];
  const float* proj_w = (const float*)d_in[6];
  const float* proj_b = (const float*)d_in[7];
  const float* n2g    = (const float*)d_in[8];
  const float* n2b    = (const float*)d_in[9];
  const float* fc1_w  = (const float*)d_in[10];
  const float* fc1_b  = (const float*)d_in[11];
  const float* fc2_w  = (const float*)d_in[12];
  const float* fc2_b  = (const float*)d_in[13];
  float* out = (float*)d_out;
  char* ws = (char*)d_ws;

  const size_t PL = (size_t)TOKS * CDIM * 2;            // 25,690,112 B
  const size_t MBSZ = (size_t)8 * 8 * NTOK * BKP;       // 10,035,200 B (fp8)
  u16*   wins = (u16*)(ws);
  u16*   aout = (u16*)(ws + PL);
  u8*    mbuf = (u8*)(ws + 2 * PL);
  u16*   qbuf = (u16*)(ws + 2 * PL + MBSZ);
  u16*   kbuf = (u16*)(ws + 4 * PL);
  u16*   vbuf = (u16*)(ws + 5 * PL);
  u16*   xres = (u16*)(ws + 4 * PL);                    // bf16; kbuf dead by proj
  u16*   h2   = (u16*)(ws + 6 * PL);
  u16*   wq   = (u16*)(ws + 7 * PL);
  u16*   y1   = (u16*)(ws);

  wconv_kernel<<<3072, 256, 0, stream>>>(qkv_w, proj_w, fc1_w, fc2_w, wq);
  mb_kernel<<<(8 * NTOK * BKP + 255) / 256, 256, 0, stream>>>(rel, mbuf);
  ln1_kernel<<<TOKS / 4, 256, 0, stream>>>(x, n1g, n1b, wins);
  gemm_bt<256><<<2352, 256, 0, stream>>>(wins, wq, 6, EpiQKV{qkv_b, qbuf, kbuf, vbuf});
  attn_kernel<<<1024, 256, 0, stream>>>(qbuf, kbuf, vbuf, mbuf, aout);
  gemm_bt<256><<<784, 256, 0, stream>>>(aout, wq + 196608, 2, EpiProj{proj_b, x, xres});
  ln2_kernel<<<TOKS / 4, 256, 0, stream>>>(xres, n2g, n2b, h2);
  gemm_bt<256><<<3136, 256, 0, stream>>>(h2, wq + 262144, 8, EpiFC1{fc1_b, y1});
  gemm_bt<1024><<<784, 256, 0, stream>>>(y1, wq + 524288, 2, EpiFC2{fc2_b, xres, out});
}

// Round 17
// 268.229 us; speedup vs baseline: 2.0230x; 1.0154x over previous
//
#include <hip/hip_runtime.h>
#include <hip/hip_bf16.h>

typedef unsigned char u8;
typedef unsigned short u16;
typedef unsigned int u32;
typedef float f32x2 __attribute__((ext_vector_type(2)));
typedef float f32x4 __attribute__((ext_vector_type(4)));
typedef short bf16x8 __attribute__((ext_vector_type(8)));
typedef short bf16x4 __attribute__((ext_vector_type(4)));
typedef unsigned int u32x4 __attribute__((ext_vector_type(4)));

#define NTOK 392      // tokens per window (8*7*7)
#define CDIM 256
#define TOKS 50176    // total tokens (= 128 windows * 392)
#define BKP  400      // padded key stride (elements) in masked-bias table
#define VTP  408      // padded Vt LDS row (k dim)
#define LOG2E 1.4426950408889634f

__device__ __forceinline__ u16 f2b(float x) {
  union { __hip_bfloat16 b; u16 u; } cv; cv.b = __float2bfloat16(x); return cv.u;
}
__device__ __forceinline__ float b2f(u16 u) {
  union { unsigned int i; float f; } c; c.i = ((unsigned int)u) << 16; return c.f;
}
__device__ __forceinline__ float exp2_fast(float x) {
#if __has_builtin(__builtin_amdgcn_exp2f)
  return __builtin_amdgcn_exp2f(x);
#else
  float r; asm("v_exp_f32 %0, %1" : "=v"(r) : "v"(x)); return r;
#endif
}

// ---- fp8 e4m3fn encode (cold) / decode (hot) ----
__device__ __forceinline__ u8 f2e4m3(float x) {
  float ax = fabsf(x);
  u32 s = (x < 0.f) ? 0x80u : 0u;
  if (ax >= 448.f) return (u8)(s | 0x7E);        // clamp to +-448 (max finite)
  int e; float m = frexpf(ax, &e);               // ax = m * 2^e, m in [0.5,1)
  int E = e - 1;
  if (E < -6) {                                  // subnormal: val = q * 2^-9
    int q = (int)rintf(ax * 512.f);
    return (u8)(s | q);
  }
  int q = (int)rintf(m * 16.f) - 8;              // 0..8
  if (q == 8) { q = 0; E += 1; if (E > 8) return (u8)(s | 0x7E); }
  return (u8)(s | ((E + 7) << 3) | q);
}
__device__ __forceinline__ float e4m3f(u32 b) {
  u32 s = (b & 0x80u) << 24;
  u32 e = (b >> 3) & 15u, m = b & 7u;
  if (e) { union { u32 u; float f; } c; c.u = s | ((e + 120u) << 23) | (m << 20); return c.f; }
  float v = (float)m * 0x1p-9f;
  return s ? -v : v;
}
__device__ __forceinline__ void fp8x4_to_f32x4(u32 w, f32x4* out) {
#if __has_builtin(__builtin_amdgcn_cvt_pk_f32_fp8)
  f32x2 lo = __builtin_amdgcn_cvt_pk_f32_fp8(w, false);
  f32x2 hi = __builtin_amdgcn_cvt_pk_f32_fp8(w, true);
  (*out)[0] = lo[0]; (*out)[1] = lo[1]; (*out)[2] = hi[0]; (*out)[3] = hi[1];
#else
  (*out)[0] = e4m3f(w & 255); (*out)[1] = e4m3f((w >> 8) & 255);
  (*out)[2] = e4m3f((w >> 16) & 255); (*out)[3] = e4m3f(w >> 24);
#endif
}

__device__ __forceinline__ f32x4 mfma16(bf16x4 a, bf16x4 b, f32x4 c) {
#if __has_builtin(__builtin_amdgcn_mfma_f32_16x16x16bf16_1k)
  return __builtin_amdgcn_mfma_f32_16x16x16bf16_1k(a, b, c, 0, 0, 0);
#else
  asm volatile("v_mfma_f32_16x16x16_bf16 %0, %1, %2, %0"
               : "+v"(c) : "v"(a), "v"(b));
  return c;
#endif
}

// ---------------- fused preprocessing: wconv (3072 blk) + mb (4900 blk) + ln1 ----------------
// All three are independent (read only inputs, write disjoint buffers).
__global__ __launch_bounds__(256) void pre_kernel(
    const float* __restrict__ qkv_w, const float* __restrict__ proj_w,
    const float* __restrict__ fc1_w, const float* __restrict__ fc2_w,
    u16* __restrict__ wq,
    const float* __restrict__ rel, u8* __restrict__ mb,
    const float* __restrict__ x, const float* __restrict__ n1g,
    const float* __restrict__ n1b, u16* __restrict__ wins) {
  const int b = blockIdx.x, tid = threadIdx.x;
  if (b < 3072) {                       // ---- weight convert ----
    int i = b * 256 + tid;
    const float* src; int off;
    if (i < 196608)      { src = qkv_w; off = i; }
    else if (i < 262144) { src = proj_w; off = i - 196608; }
    else if (i < 524288) { src = fc1_w; off = i - 262144; }
    else                 { src = fc2_w; off = i - 524288; }
    wq[i] = f2b(src[off]);
    return;
  }
  if (b < 3072 + 4900) {                // ---- masked-bias table ----
    int idx = (b - 3072) * 256 + tid;   // over 8 * 392 * 400
    int pat = idx / (NTOK * BKP);
    int r   = idx % (NTOK * BKP);
    int q = r / BKP, k = r % BKP;
    int pd = (pat >> 2) & 1, ph = (pat >> 1) & 1, pw = pat & 1;
    if (k >= NTOK) {
      #pragma unroll
      for (int h = 0; h < 8; ++h)
        mb[((size_t)(pat * 8 + h) * NTOK + q) * BKP + k] = 0xFE;  // -448 -> exp2 ~ 0
      return;
    }
    int td = q / 49, th = (q % 49) / 7, tw = q % 7;
    int md = k / 49, mh = (k % 49) / 7, mw = k % 7;
    int cq = (pd ? (td < 4 ? 1 : 2) : 0) * 9 + (ph ? (th < 4 ? 1 : 2) : 0) * 3 + (pw ? (tw < 4 ? 1 : 2) : 0);
    int ck = (pd ? (md < 4 ? 1 : 2) : 0) * 9 + (ph ? (mh < 4 ? 1 : 2) : 0) * 3 + (pw ? (mw < 4 ? 1 : 2) : 0);
    float mask = (cq == ck) ? 0.f : -100.f;
    int ridx = (td - md + 7) * 169 + (th - mh + 6) * 13 + (tw - mw + 6);
    const float* rp = rel + (size_t)ridx * 8;
    #pragma unroll
    for (int h = 0; h < 8; ++h)
      mb[((size_t)(pat * 8 + h) * NTOK + q) * BKP + k] = f2e4m3((rp[h] + mask) * LOG2E);
    return;
  }
  // ---- LN1 fused roll+window-partition (4 tokens/block) ----
  const int t = (b - 7972) * 4 + (tid >> 6), lane = tid & 63;
  int w = t / NTOK, n = t % NTOK;
  int wd = w >> 6, wh = (w >> 3) & 7, ww = w & 7;
  int td = n / 49, rr = n % 49, th = rr / 7, tw = rr % 7;
  int d  = (wd * 8 + td + 4) & 15;
  int hh = (wh * 7 + th + 3) % 56;
  int wc = (ww * 7 + tw + 3) % 56;
  size_t src = ((size_t)((d * 56 + hh) * 56 + wc)) * CDIM;
  f32x4 v = *(const f32x4*)(x + src + lane * 4);
  float s  = v[0] + v[1] + v[2] + v[3];
  float s2 = v[0]*v[0] + v[1]*v[1] + v[2]*v[2] + v[3]*v[3];
  #pragma unroll
  for (int o = 1; o < 64; o <<= 1) { s += __shfl_xor(s, o); s2 += __shfl_xor(s2, o); }
  float mean = s * (1.f / CDIM);
  float var  = s2 * (1.f / CDIM) - mean * mean;
  float rs   = rsqrtf(var + 1e-5f);
  f32x4 gg = *(const f32x4*)(n1g + lane * 4);
  f32x4 bb = *(const f32x4*)(n1b + lane * 4);
  bf16x4 o4;
  #pragma unroll
  for (int j = 0; j < 4; ++j) o4[j] = (short)f2b((v[j] - mean) * rs * gg[j] + bb[j]);
  *(bf16x4*)(wins + (size_t)t * CDIM + lane * 4) = o4;
}

// ---------------- LN2: bf16 in, linear, 4 tokens/block ----------------
__global__ __launch_bounds__(256) void ln2_kernel(const u16* __restrict__ x,
    const float* __restrict__ g, const float* __restrict__ b,
    u16* __restrict__ out) {
  const int t = blockIdx.x * 4 + (threadIdx.x >> 6), lane = threadIdx.x & 63;
  bf16x4 v4 = *(const bf16x4*)(x + (size_t)t * CDIM + lane * 4);
  f32x4 v;
  #pragma unroll
  for (int j = 0; j < 4; ++j) v[j] = b2f((u16)v4[j]);
  float s  = v[0] + v[1] + v[2] + v[3];
  float s2 = v[0]*v[0] + v[1]*v[1] + v[2]*v[2] + v[3]*v[3];
  #pragma unroll
  for (int o = 1; o < 64; o <<= 1) { s += __shfl_xor(s, o); s2 += __shfl_xor(s2, o); }
  float mean = s * (1.f / CDIM);
  float var  = s2 * (1.f / CDIM) - mean * mean;
  float rs   = rsqrtf(var + 1e-5f);
  f32x4 gg = *(const f32x4*)(g + lane * 4);
  f32x4 bb = *(const f32x4*)(b + lane * 4);
  bf16x4 o4;
  #pragma unroll
  for (int j = 0; j < 4; ++j) o4[j] = (short)f2b((v[j] - mean) * rs * gg[j] + bb[j]);
  *(bf16x4*)(out + (size_t)t * CDIM + lane * 4) = o4;
}

// ---------------- generic bf16 GEMM: C[M][N] = A[M][K] * B[N][K]^T ----------------
// m97 structure + XCD remap + 4 blocks/CU (VGPR cap 128 >= 88 needed; (256,5)
// capped VGPR at 48 -> spills). MFMA operands SWAPPED (computes C^T): per lane
// acc[mi][ni] holds row bm+wm+mi*16+l16 x 4 contiguous cols -> vector stores.
template<int K, class Epi>
__global__ __launch_bounds__(256, 4) void gemm_bt(const u16* __restrict__ A,
    const u16* __restrict__ B, int nx, Epi epi) {
  __shared__ __align__(16) u16 As[128 * 64];
  __shared__ __align__(16) u16 Bs[128 * 64];
  const int nwg = gridDim.x;
  const int q8 = nwg >> 3, r8 = nwg & 7;
  const int xcd = blockIdx.x & 7, bix = blockIdx.x >> 3;
  const int logical = (xcd < r8) ? (xcd * (q8 + 1) + bix)
                                 : (r8 * (q8 + 1) + (xcd - r8) * q8 + bix);
  const int bm = (logical / nx) * 128, bn = (logical % nx) * 128;
  const int tid = threadIdx.x, lane = tid & 63, wv = tid >> 6;
  const int wm = (wv >> 1) * 64, wn = (wv & 1) * 64;
  const int l16 = lane & 15, g = lane >> 4;
  const int sw = l16 & 7;
  const int srow = (lane >> 3);             // row within 8-row group
  const int scc  = (lane & 7) ^ srow;       // swizzled source chunk
  f32x4 acc[4][4];
  #pragma unroll
  for (int i = 0; i < 4; ++i)
    #pragma unroll
    for (int j = 0; j < 4; ++j) acc[i][j] = (f32x4){0.f, 0.f, 0.f, 0.f};
  #pragma unroll
  for (int k0 = 0; k0 < K; k0 += 64) {
    #pragma unroll
    for (int c = 0; c < 4; ++c) {
      int row = wv * 32 + c * 8 + srow;
      const u16* ga = A + (size_t)(bm + row) * K + k0 + scc * 8;
      const u16* gb = B + (size_t)(bn + row) * K + k0 + scc * 8;
      __builtin_amdgcn_global_load_lds(
          (const __attribute__((address_space(1))) void*)ga,
          (__attribute__((address_space(3))) void*)(As + (wv * 32 + c * 8) * 64), 16, 0, 0);
      __builtin_amdgcn_global_load_lds(
          (const __attribute__((address_space(1))) void*)gb,
          (__attribute__((address_space(3))) void*)(Bs + (wv * 32 + c * 8) * 64), 16, 0, 0);
    }
    __syncthreads();
    #pragma unroll
    for (int kk = 0; kk < 2; ++kk) {
      bf16x8 fa[4], fb[4];
      #pragma unroll
      for (int i = 0; i < 4; ++i)
        fa[i] = *(const bf16x8*)(As + (wm + i * 16 + l16) * 64 + (((kk * 4 + g) ^ sw) * 8));
      #pragma unroll
      for (int i = 0; i < 4; ++i)
        fb[i] = *(const bf16x8*)(Bs + (wn + i * 16 + l16) * 64 + (((kk * 4 + g) ^ sw) * 8));
      #pragma unroll
      for (int mi = 0; mi < 4; ++mi)
        #pragma unroll
        for (int ni = 0; ni < 4; ++ni)
          acc[mi][ni] = __builtin_amdgcn_mfma_f32_16x16x32_bf16(fb[ni], fa[mi], acc[mi][ni], 0, 0, 0);
    }
    __syncthreads();
  }
  #pragma unroll
  for (int mi = 0; mi < 4; ++mi) {
    const int row = bm + wm + mi * 16 + l16;
    #pragma unroll
    for (int ni = 0; ni < 4; ++ni)
      epi(row, bn + wn + ni * 16 + g * 4, acc[mi][ni]);
  }
}

// ---------------- epilogues (receive 4 contiguous cols per call) ----------------
struct EpiQKV {  // q/k: [w][h][n][32] (bf16x4 store); v: [w][h][32][n] (4 strided)
  const float* __restrict__ qb;
  u16 *q, *k, *v;
  __device__ void operator()(int row, int col, f32x4 val) const {
    f32x4 b4 = *(const f32x4*)(qb + col);
    int which = col >> 8, hd = col & 255;
    int head = hd >> 5, d = hd & 31;
    int w = row / NTOK, n = row - w * NTOK;
    if (which == 2) {
      u16* p = v + (((size_t)w * 8 + head) * 32 + d) * NTOK + n;
      #pragma unroll
      for (int j = 0; j < 4; ++j) p[(size_t)j * NTOK] = f2b(val[j] + b4[j]);
    } else {
      const float sc = (which == 0) ? 0.17677669529663687f * LOG2E : 1.f;
      bf16x4 o;
      #pragma unroll
      for (int j = 0; j < 4; ++j) o[j] = (short)f2b((val[j] + b4[j]) * sc);
      u16* p = (which == 0 ? q : k) + (((size_t)w * 8 + head) * NTOK + n) * 32 + d;
      *(bf16x4*)p = o;
    }
  }
};

struct EpiProj {  // +bias, reverse-partition + unroll, + residual x -> xres (bf16)
  const float* __restrict__ pb;
  const float* __restrict__ x;
  u16* xr;
  __device__ void operator()(int row, int col, f32x4 val) const {
    f32x4 b4 = *(const f32x4*)(pb + col);
    int w = row / NTOK, n = row - w * NTOK;
    int wd = w >> 6, wh = (w >> 3) & 7, ww = w & 7;
    int td = n / 49, rr = n % 49, th = rr / 7, tw = rr % 7;
    int d  = (wd * 8 + td + 4) & 15;
    int hh = (wh * 7 + th + 3) % 56;
    int wc = (ww * 7 + tw + 3) % 56;
    size_t t = ((size_t)((d * 56 + hh) * 56 + wc)) * CDIM + col;
    f32x4 xv = *(const f32x4*)(x + t);
    bf16x4 o;
    #pragma unroll
    for (int j = 0; j < 4; ++j) o[j] = (short)f2b(xv[j] + val[j] + b4[j]);
    *(bf16x4*)(xr + t) = o;
  }
};

struct EpiFC1 {  // +bias, exact GELU, bf16x4 store (row stride 1024)
  const float* __restrict__ fb;
  u16* y;
  __device__ void operator()(int row, int col, f32x4 val) const {
    f32x4 b4 = *(const f32x4*)(fb + col);
    bf16x4 o;
    #pragma unroll
    for (int j = 0; j < 4; ++j) {
      float u = val[j] + b4[j];
      u = 0.5f * u * (1.0f + erff(u * 0.70710678118654752f));
      o[j] = (short)f2b(u);
    }
    *(bf16x4*)(y + (size_t)row * 1024 + col) = o;
  }
};

struct EpiFC2 {  // +bias, + residual xres (bf16), fp32x4 final out
  const float* __restrict__ fb;
  const u16* __restrict__ xr;
  float* out;
  __device__ void operator()(int row, int col, f32x4 val) const {
    f32x4 b4 = *(const f32x4*)(fb + col);
    size_t t = (size_t)row * CDIM + col;
    bf16x4 xv = *(const bf16x4*)(xr + t);
    f32x4 o;
    #pragma unroll
    for (int j = 0; j < 4; ++j) o[j] = b2f((u16)xv[j]) + val[j] + b4[j];
    *(f32x4*)(out + t) = o;
  }
};

// ---------------- window attention (round-13 known-good structure) ----------------
// Block-synchronous q-tile rounds with T14 async-STAGE split for the mb slice.
// Ms stride 400 (x4-aligned -> single ds_write_b128 staging); Ks XOR-swizzled.
__global__ __launch_bounds__(256, 2) void attn_kernel(
    const u16* __restrict__ qb, const u16* __restrict__ kb,
    const u16* __restrict__ vb, const u8* __restrict__ mb,
    u16* __restrict__ out) {
  __shared__ __align__(16) u16 Ks[25 * 512];     // 25600 B
  __shared__ __align__(16) u16 Vt[32 * VTP];     // 26112 B
  __shared__ __align__(16) u8  Ms[64 * BKP];     // 25600 B fp8 slice
  const int h = blockIdx.x & 7;
  const int r = blockIdx.x >> 3;
  const int cum[9] = {0, 49, 56, 63, 64, 113, 120, 127, 128};
  int pat = 0;
  #pragma unroll
  for (int p = 0; p < 8; ++p) pat += (r >= cum[p + 1]) ? 1 : 0;
  const int i = r - cum[pat];
  const int pd = (pat >> 2) & 1, ph = (pat >> 1) & 1, pw = pat & 1;
  const int nw = pw ? 1 : 7;
  const int wh = ph ? 7 : i / nw;
  const int ww = pw ? 7 : i % nw;
  const int w = pd * 64 + wh * 8 + ww;

  const int tid = threadIdx.x, lane = tid & 63, wv = tid >> 6;
  const size_t base = (size_t)(w * 8 + h) * (NTOK * 32);
  const u8* mplane = mb + (size_t)(pat * 8 + h) * NTOK * BKP;

  // zero Vt pad cols (keys 392..407)
  for (int idx = tid; idx < 32 * 16; idx += 256)
    Vt[(idx >> 4) * VTP + NTOK + (idx & 15)] = 0;
  // stage K tiled+swizzled (400 rows; rows>=392 clamp -> finite; bias kills them)
  for (int c = tid; c < 400 * 4; c += 256) {
    int rr = c >> 2, cb = c & 3;
    int rs = rr < NTOK ? rr : NTOK - 1;
    *(bf16x8*)(Ks + (rr >> 4) * 512 + cb * 128 + (((rr & 15) ^ (cb << 1)) * 8)) =
        *(const bf16x8*)(kb + base + (size_t)rs * 32 + cb * 8);
  }
  // stage V rows (vbuf pre-transposed [w][h][32][392]): coalesced copies
  for (int c = tid; c < 32 * 49; c += 256) {
    int d = c / 49, ch = c % 49;
    *(bf16x8*)(Vt + d * VTP + ch * 8) =
        *(const bf16x8*)(vb + base + (size_t)d * NTOK + ch * 8);
  }

  // prefetch round-0 mb slice into registers (1600 x 16B chunks)
  u32x4 pf[7];
  #pragma unroll
  for (int j = 0; j < 7; ++j) {
    int idx = tid + j * 256;
    if (idx < 1600) {
      int row = idx / 25, cb = idx % 25;
      pf[j] = *(const u32x4*)(mplane + (size_t)row * BKP + cb * 16);
    }
  }

  const int l16 = lane & 15, g = lane >> 4;
  for (int round = 0; round < 7; ++round) {
    // write this round's slice to LDS (prior round's reads fenced by loop-end barrier)
    #pragma unroll
    for (int j = 0; j < 7; ++j) {
      int idx = tid + j * 256;
      if (idx < 1600) {
        int row = idx / 25, cb = idx % 25;
        *(u32x4*)(Ms + row * BKP + cb * 16) = pf[j];
      }
    }
    // issue next round's loads (overlap with compute below)
    if (round < 6) {
      #pragma unroll
      for (int j = 0; j < 7; ++j) {
        int idx = tid + j * 256;
        if (idx < 1600) {
          int row = idx / 25, cb = idx % 25;
          int qrow = (round + 1) * 64 + row; qrow = qrow < NTOK ? qrow : NTOK - 1;
          pf[j] = *(const u32x4*)(mplane + (size_t)qrow * BKP + cb * 16);
        }
      }
    }
    __syncthreads();
    const int qt = round * 4 + wv;
    if (qt < 25) {
      const int qq = qt * 16 + l16;
      const int qc = qq < NTOK ? qq : NTOK - 1;
      const bf16x8 qf = *(const bf16x8*)(qb + base + (size_t)qc * 32 + g * 8);
      const u8* mrow = Ms + (wv * 16 + l16) * BKP + 4 * g;
      f32x4 o00 = {0.f,0.f,0.f,0.f}, o01 = {0.f,0.f,0.f,0.f};
      f32x4 o10 = {0.f,0.f,0.f,0.f}, o11 = {0.f,0.f,0.f,0.f};
      float psum = 0.f;
      #pragma unroll
      for (int t = 0; t < 25; ++t) {
        bf16x8 kf = *(const bf16x8*)(Ks + t * 512 + g * 128 + ((l16 ^ (g << 1)) * 8));
        u32 mw = *(const u32*)(mrow + t * 16);
        f32x4 c;
        fp8x4_to_f32x4(mw, &c);
        f32x4 st = __builtin_amdgcn_mfma_f32_16x16x32_bf16(kf, qf, c, 0, 0, 0);
        float p0 = exp2_fast(st[0]), p1 = exp2_fast(st[1]);
        float p2 = exp2_fast(st[2]), p3 = exp2_fast(st[3]);
        psum += (p0 + p1) + (p2 + p3);
        bf16x4 pfv;
        pfv[0] = (short)f2b(p0); pfv[1] = (short)f2b(p1);
        pfv[2] = (short)f2b(p2); pfv[3] = (short)f2b(p3);
        bf16x4 v0 = *(const bf16x4*)(Vt + l16 * VTP + t * 16 + 4 * g);
        bf16x4 v1 = *(const bf16x4*)(Vt + (16 + l16) * VTP + t * 16 + 4 * g);
        if (t & 1) { o01 = mfma16(v0, pfv, o01); o11 = mfma16(v1, pfv, o11); }
        else       { o00 = mfma16(v0, pfv, o00); o10 = mfma16(v1, pfv, o10); }
      }
      psum += __shfl_xor(psum, 16);
      psum += __shfl_xor(psum, 32);
      if (qq < NTOK) {
        float inv = 1.f / psum;
        bf16x4 w0, w1;
        #pragma unroll
        for (int j = 0; j < 4; ++j) {
          w0[j] = (short)f2b((o00[j] + o01[j]) * inv);
          w1[j] = (short)f2b((o10[j] + o11[j]) * inv);
        }
        u16* op = out + ((size_t)(w * NTOK + qq)) * CDIM + h * 32;
        *(bf16x4*)(op + 4 * g) = w0;
        *(bf16x4*)(op + 16 + 4 * g) = w1;
      }
    }
    __syncthreads();
  }
}

// ---------------- launcher ----------------
extern "C" void kernel_launch(void* const* d_in, const int* in_sizes, int n_in,
                              void* d_out, int out_size, void* d_ws, size_t ws_size,
                              hipStream_t stream) {
  const float* x      = (const float*)d_in[0];
  const float* n1g    = (const float*)d_in[1];
  const float* n1b    = (const float*)d_in[2];
  const float* qkv_w  = (const float*)d_in[3];
  const float* qkv_b  = (const float*)d_in[4];
  const float* rel    = (const float*)d_in[5];
  const float* proj_w = (const float*)d_in[6];
  const float* proj_b = (const float*)d_in[7];
  const float* n2g    = (const float*)d_in[8];
  const float* n2b    = (const float*)d_in[9];
  const float* fc1_w  = (const float*)d_in[10];
  const float* fc1_b  = (const float*)d_in[11];
  const float* fc2_w  = (const float*)d_in[12];
  const float* fc2_b  = (const float*)d_in[13];
  float* out = (float*)d_out;
  char* ws = (char*)d_ws;

  const size_t PL = (size_t)TOKS * CDIM * 2;            // 25,690,112 B
  const size_t MBSZ = (size_t)8 * 8 * NTOK * BKP;       // 10,035,200 B (fp8)
  u16*   wins = (u16*)(ws);
  u16*   aout = (u16*)(ws + PL);
  u8*    mbuf = (u8*)(ws + 2 * PL);
  u16*   qbuf = (u16*)(ws + 2 * PL + MBSZ);
  u16*   kbuf = (u16*)(ws + 4 * PL);
  u16*   vbuf = (u16*)(ws + 5 * PL);
  u16*   xres = (u16*)(ws + 4 * PL);                    // bf16; kbuf dead by proj
  u16*   h2   = (u16*)(ws + 6 * PL);
  u16*   wq   = (u16*)(ws + 7 * PL);
  u16*   y1   = (u16*)(ws);

  // fused preprocessing: 3072 (wconv) + 4900 (mb) + 12544 (ln1) blocks
  pre_kernel<<<3072 + 4900 + TOKS / 4, 256, 0, stream>>>(
      qkv_w, proj_w, fc1_w, fc2_w, wq, rel, mbuf, x, n1g, n1b, wins);
  gemm_bt<256><<<2352, 256, 0, stream>>>(wins, wq, 6, EpiQKV{qkv_b, qbuf, kbuf, vbuf});
  attn_kernel<<<1024, 256, 0, stream>>>(qbuf, kbuf, vbuf, mbuf, aout);
  gemm_bt<256><<<784, 256, 0, stream>>>(aout, wq + 196608, 2, EpiProj{proj_b, x, xres});
  ln2_kernel<<<TOKS / 4, 256, 0, stream>>>(xres, n2g, n2b, h2);
  gemm_bt<256><<<3136, 256, 0, stream>>>(h2, wq + 262144, 8, EpiFC1{fc1_b, y1});
  gemm_bt<1024><<<784, 256, 0, stream>>>(y1, wq + 524288, 2, EpiFC2{fc2_b, xres, out});
}